// Round 2
// 2175.269 us; speedup vs baseline: 1.0006x; 1.0006x over previous
//
#include <hip/hip_runtime.h>
#include <cstdint>
#include <cstddef>

// ---------------------------------------------------------------------------
// SparseCINConv, MFMA edition: CSR-gather fused into first GEMM, all GEMMs on
// mfma_f32_16x16x32_bf16 (fp32 accumulate), intermediates stored bf16,
// BN batch-stats accumulated fp32 in GEMM epilogues.
// R1: (a) mode-0 gather restructured for memory-level parallelism:
//     one coalesced 16-wide index load per row + 4-wide independent row
//     gathers (was: serial 2-wide with dependent esrc->gather chains).
//     (b) CSR build fused across the 4 edge sets: one concatenated count
//     array, one global 3-phase scan, one hist + one fill kernel
//     (24 dispatches -> 6).
// R2: identical resubmit of R1 (container-level failure, audit clean).
// ---------------------------------------------------------------------------

using bfrag = __attribute__((ext_vector_type(8))) short;   // 8 bf16 (4 VGPRs)
using f32x4 = __attribute__((ext_vector_type(4))) float;   // 4 fp32 acc

__device__ __forceinline__ unsigned short f2bf(float f) {
    unsigned int u = __float_as_uint(f);
    u += 0x7FFFu + ((u >> 16) & 1u);          // RNE
    return (unsigned short)(u >> 16);
}
__device__ __forceinline__ float bf2f(unsigned int h) {
    return __uint_as_float(h << 16);
}

// ---------------- fused CSR build (4 concatenated edge sets) ----------------

__global__ __launch_bounds__(256) void hist_all_k(
    const int* __restrict__ d0, const int* __restrict__ d1,
    const int* __restrict__ d2, const int* __restrict__ d3,
    int E0, int E1, int E2, int E3,
    int o0, int o1, int o2, int o3, int* __restrict__ cnt)
{
    int e = blockIdx.x * 256 + threadIdx.x;
    if (e < E0) { atomicAdd(&cnt[o0 + d0[e]], 1); return; }
    e -= E0;
    if (e < E1) { atomicAdd(&cnt[o1 + d1[e]], 1); return; }
    e -= E1;
    if (e < E2) { atomicAdd(&cnt[o2 + d2[e]], 1); return; }
    e -= E2;
    if (e < E3) atomicAdd(&cnt[o3 + d3[e]], 1);
}

// 2048 elements / block (8 per thread) so one scanB level covers 1M counters.
__global__ __launch_bounds__(256) void scanA_k(int* __restrict__ a,
                                               int* __restrict__ bsum, int n) {
    __shared__ int ts[256];
    int tid = threadIdx.x;
    int base = blockIdx.x * 2048 + tid * 8;
    int v[8]; int s = 0;
    #pragma unroll
    for (int i = 0; i < 8; ++i) { v[i] = (base + i < n) ? a[base + i] : 0; s += v[i]; }
    ts[tid] = s;
    __syncthreads();
    for (int off = 1; off < 256; off <<= 1) {
        int t = (tid >= off) ? ts[tid - off] : 0;
        __syncthreads();
        ts[tid] += t;
        __syncthreads();
    }
    int run = ts[tid] - s;
    #pragma unroll
    for (int i = 0; i < 8; ++i) {
        if (base + i < n) { int o = v[i]; a[base + i] = run; run += o; }
    }
    if (tid == 255) bsum[blockIdx.x] = ts[255];
}

__global__ __launch_bounds__(512) void scanB_k(int* __restrict__ bsum, int nb) {
    __shared__ int ls[512];
    int tid = threadIdx.x;
    int v = (tid < nb) ? bsum[tid] : 0;
    ls[tid] = v;
    __syncthreads();
    for (int off = 1; off < 512; off <<= 1) {
        int t = (tid >= off) ? ls[tid - off] : 0;
        __syncthreads();
        ls[tid] += t;
        __syncthreads();
    }
    if (tid < nb) bsum[tid] = ls[tid] - v;
}

__global__ __launch_bounds__(256) void scanC_k(int* __restrict__ a,
                                               const int* __restrict__ bsum, int n) {
    int base = blockIdx.x * 2048 + threadIdx.x * 8;
    int add = bsum[blockIdx.x];
    #pragma unroll
    for (int i = 0; i < 8; ++i)
        if (base + i < n) a[base + i] += add;
}

__global__ __launch_bounds__(256) void fill_all_k(
    const int* __restrict__ s0, const int* __restrict__ d0,
    const int* __restrict__ s1, const int* __restrict__ d1,
    const int* __restrict__ s2, const int* __restrict__ d2,
    const int* __restrict__ s3, const int* __restrict__ d3,
    int E0, int E1, int E2, int E3,
    int o0, int o1, int o2, int o3,
    int* __restrict__ cur, int* __restrict__ esrc)
{
    int e = blockIdx.x * 256 + threadIdx.x;
    const int* sp; const int* dp; int off;
    if (e < E0) { sp = s0; dp = d0; off = o0; }
    else {
        e -= E0;
        if (e < E1) { sp = s1; dp = d1; off = o1; }
        else {
            e -= E1;
            if (e < E2) { sp = s2; dp = d2; off = o2; }
            else {
                e -= E2;
                if (e >= E3) return;
                sp = s3; dp = d3; off = o3;
            }
        }
    }
    int pos = atomicAdd(&cur[off + dp[e]], 1);
    esrc[pos] = sp[e];
}

// ---------------- weight prep: fp32 [K][64] -> bf16 transposed [64][K] -------

__global__ __launch_bounds__(256) void wprep_k(
    const float* __restrict__ upW1, const float* __restrict__ upW2,
    const float* __restrict__ bdW1, const float* __restrict__ bdW2,
    const float* __restrict__ cmbW, unsigned short* __restrict__ wT)
{
    int id = blockIdx.x;        // 0..14 = d*5 + j
    int d = id / 5, j = id % 5;
    const float* src; int K = 64;
    if (j == 0)      src = upW1 + (size_t)d * 4096;
    else if (j == 1) src = upW2 + (size_t)d * 4096;
    else if (j == 2) src = bdW1 + (size_t)d * 4096;
    else if (j == 3) src = bdW2 + (size_t)d * 4096;
    else           { src = cmbW + (size_t)d * 8192; K = 128; }
    unsigned short* dst = wT + (size_t)d * 24576 + (j < 4 ? j * 4096 : 16384);
    for (int e = threadIdx.x; e < K * 64; e += 256) {
        int k = e >> 6, n = e & 63;
        dst[n * K + k] = f2bf(src[e]);
    }
}

// ---------------- fused MFMA GEMM + BN-stats ----------------
// mode 0: A = csr_gather(xs) + (1+eps)*xself   (fp32 in, K=64)
// mode 1: A = relu(bn(in0))                     (bf16 in, K=64)
// mode 2: A = concat(relu(bn(in0)),relu(bn(in1))) (bf16 in, K=128)
// out(bf16) = A @ W + bias ; ostats += {colsum, colsumsq} (fp32)
__global__ __launch_bounds__(256) void gemm_bn_k(
    int mode,
    const int* __restrict__ cur, const int* __restrict__ esrc, int eBase,
    const float* __restrict__ xs, const float* __restrict__ xself,
    const unsigned short* __restrict__ in0, const unsigned short* __restrict__ in1,
    const float* __restrict__ st0, const float* __restrict__ g0, const float* __restrict__ be0,
    const float* __restrict__ st1, const float* __restrict__ g1, const float* __restrict__ be1,
    const float* __restrict__ epsP, int epsIdx,
    const unsigned short* __restrict__ wT, const float* __restrict__ bias,
    unsigned short* __restrict__ out, float* __restrict__ ostats, int N)
{
    __shared__ unsigned short sIn[64][72];  // +8 pad: fragment reads 2-way (free)
    __shared__ unsigned short sW[64][72];   // W transposed [n][k]
    __shared__ float sCoef[4][64];
    __shared__ float sBias[64];
    __shared__ float sRedS[4][64];
    __shared__ float sRedQ[4][64];

    const int tid = threadIdx.x;
    const int row0 = blockIdx.x * 64;
    const float Nf = (float)N;

    if (tid < 64) {
        sBias[tid] = bias[tid];
        if (mode >= 1) {
            float s = st0[tid], sq = st0[64 + tid];
            float m = s / Nf, v = sq / Nf - m * m;
            float a = g0[tid] * rsqrtf(v + 1e-5f);
            sCoef[0][tid] = a; sCoef[1][tid] = be0[tid] - a * m;
        }
    } else if (tid < 128 && mode == 2) {
        int k = tid - 64;
        float s = st1[k], sq = st1[64 + k];
        float m = s / Nf, v = sq / Nf - m * m;
        float a = g1[k] * rsqrtf(v + 1e-5f);
        sCoef[2][k] = a; sCoef[3][k] = be1[k] - a * m;
    }
    const float sx = (mode == 0) ? (1.0f + epsP[epsIdx]) : 0.f;
    __syncthreads();

    f32x4 acc[4] = {};
    const int K = (mode == 2) ? 128 : 64;
    const int nch = (mode == 2) ? 2 : 1;
    const int wv = tid >> 6, l = tid & 63, l15 = l & 15, quad = l >> 4;

    for (int ch = 0; ch < nch; ++ch) {
        if (ch) __syncthreads();   // LDS reuse between chunks
        if (mode == 0) {
            // 16-lane group per 4 rows; index-vectorized gather, 4-wide MLP.
            const int grp = tid >> 4, lane = tid & 15;
            const int r0g = row0 + grp * 4;
            float ax[4], ay[4], az[4], aw[4];
            int beg[4], deg[4];
            #pragma unroll
            for (int rr = 0; rr < 4; ++rr) {
                int gr = r0g + rr;
                float4 xv = {0.f, 0.f, 0.f, 0.f};
                if (gr < N)
                    xv = *(const float4*)(xself + (size_t)gr * 64 + lane * 4);
                ax[rr] = sx * xv.x; ay[rr] = sx * xv.y;
                az[rr] = sx * xv.z; aw[rr] = sx * xv.w;
                int b = 0, d = 0;
                if (gr < N && cur) {
                    b = (gr == 0) ? eBase : cur[gr - 1];
                    d = cur[gr] - b;
                }
                beg[rr] = b; deg[rr] = d;
            }
            #pragma unroll
            for (int rr = 0; rr < 4; ++rr) {
                for (int base = 0; base < deg[rr]; base += 16) {
                    int take = deg[rr] - base; if (take > 16) take = 16;
                    // one coalesced load fetches up to 16 edge indices
                    int idxl = 0;
                    if (lane < take) idxl = esrc[beg[rr] + base + lane];
                    for (int j0 = 0; j0 < take; j0 += 4) {
                        float4 v0 = {0,0,0,0}, v1 = {0,0,0,0};
                        float4 v2 = {0,0,0,0}, v3 = {0,0,0,0};
                        int si = __shfl(idxl, j0, 16);
                        v0 = *(const float4*)(xs + (size_t)si * 64 + lane * 4);
                        if (j0 + 1 < take) {
                            si = __shfl(idxl, j0 + 1, 16);
                            v1 = *(const float4*)(xs + (size_t)si * 64 + lane * 4);
                        }
                        if (j0 + 2 < take) {
                            si = __shfl(idxl, j0 + 2, 16);
                            v2 = *(const float4*)(xs + (size_t)si * 64 + lane * 4);
                        }
                        if (j0 + 3 < take) {
                            si = __shfl(idxl, j0 + 3, 16);
                            v3 = *(const float4*)(xs + (size_t)si * 64 + lane * 4);
                        }
                        ax[rr] += (v0.x + v1.x) + (v2.x + v3.x);
                        ay[rr] += (v0.y + v1.y) + (v2.y + v3.y);
                        az[rr] += (v0.z + v1.z) + (v2.z + v3.z);
                        aw[rr] += (v0.w + v1.w) + (v2.w + v3.w);
                    }
                }
                ushort4 pk;
                pk.x = f2bf(ax[rr]); pk.y = f2bf(ay[rr]);
                pk.z = f2bf(az[rr]); pk.w = f2bf(aw[rr]);
                *(ushort4*)&sIn[grp * 4 + rr][lane * 4] = pk;
            }
        } else {
            const unsigned short* base = ch ? in1 : in0;
            const int ci = ch * 2;
            #pragma unroll
            for (int it = 0; it < 2; ++it) {
                int id = tid + it * 256;
                int r = id >> 3, c8 = id & 7;
                int gr = row0 + r;
                uint4 pk = {0u, 0u, 0u, 0u};
                if (gr < N) {
                    uint4 raw = *(const uint4*)(base + (size_t)gr * 64 + c8 * 8);
                    unsigned int rw[4] = {raw.x, raw.y, raw.z, raw.w};
                    unsigned int ow[4];
                    #pragma unroll
                    for (int q2 = 0; q2 < 4; ++q2) {
                        int col = c8 * 8 + q2 * 2;
                        float v0 = fmaxf(fmaf(sCoef[ci][col], bf2f(rw[q2] & 0xFFFFu),
                                              sCoef[ci + 1][col]), 0.f);
                        float v1 = fmaxf(fmaf(sCoef[ci][col + 1], bf2f(rw[q2] >> 16),
                                              sCoef[ci + 1][col + 1]), 0.f);
                        ow[q2] = (unsigned int)f2bf(v0) | ((unsigned int)f2bf(v1) << 16);
                    }
                    pk.x = ow[0]; pk.y = ow[1]; pk.z = ow[2]; pk.w = ow[3];
                }
                *(uint4*)&sIn[r][c8 * 8] = pk;
            }
        }
        #pragma unroll
        for (int it = 0; it < 2; ++it) {
            int id = tid + it * 256;
            int nr = id >> 3, c8 = id & 7;
            uint4 w = *(const uint4*)(wT + (size_t)nr * K + ch * 64 + c8 * 8);
            *(uint4*)&sW[nr][c8 * 8] = w;
        }
        __syncthreads();
        // A frag: A[m=lane&15][k=quad*8+j]; B frag: B[k=quad*8+j][n=lane&15]
        bfrag a0 = *(const bfrag*)&sIn[16 * wv + l15][quad * 8];
        bfrag a1 = *(const bfrag*)&sIn[16 * wv + l15][32 + quad * 8];
        #pragma unroll
        for (int c = 0; c < 4; ++c) {
            bfrag b0 = *(const bfrag*)&sW[16 * c + l15][quad * 8];
            bfrag b1 = *(const bfrag*)&sW[16 * c + l15][32 + quad * 8];
            acc[c] = __builtin_amdgcn_mfma_f32_16x16x32_bf16(a0, b0, acc[c], 0, 0, 0);
            acc[c] = __builtin_amdgcn_mfma_f32_16x16x32_bf16(a1, b1, acc[c], 0, 0, 0);
        }
    }

    // epilogue: bias, bf16 store, fp32 column stats
    // C/D layout: col = lane&15 (+16c), row = quad*4 + reg (+16*wv)
    float psv[4], pqv[4];
    #pragma unroll
    for (int c = 0; c < 4; ++c) {
        int col = 16 * c + l15;
        float b = sBias[col];
        float ps = 0.f, pq = 0.f;
        #pragma unroll
        for (int r = 0; r < 4; ++r) {
            int grow = row0 + 16 * wv + quad * 4 + r;
            if (grow < N) {
                float v = acc[c][r] + b;
                out[(size_t)grow * 64 + col] = f2bf(v);
                ps += v; pq += v * v;
            }
        }
        psv[c] = ps; pqv[c] = pq;
    }
    #pragma unroll
    for (int c = 0; c < 4; ++c) {
        float ps = psv[c], pq = pqv[c];
        ps += __shfl_xor(ps, 16, 64); pq += __shfl_xor(pq, 16, 64);
        ps += __shfl_xor(ps, 32, 64); pq += __shfl_xor(pq, 32, 64);
        if (l < 16) { sRedS[wv][16 * c + l] = ps; sRedQ[wv][16 * c + l] = pq; }
    }
    __syncthreads();
    if (tid < 64) {
        float s = sRedS[0][tid] + sRedS[1][tid] + sRedS[2][tid] + sRedS[3][tid];
        float q = sRedQ[0][tid] + sRedQ[1][tid] + sRedQ[2][tid] + sRedQ[3][tid];
        unsafeAtomicAdd(&ostats[tid], s);
        unsafeAtomicAdd(&ostats[64 + tid], q);
    }
}

__global__ __launch_bounds__(256) void bn_relu_apply_k(
    const unsigned short* __restrict__ y, const float* __restrict__ st,
    const float* __restrict__ g, const float* __restrict__ be,
    float* __restrict__ out, int N)
{
    __shared__ float sa[64], sc[64];
    int tid = threadIdx.x;
    if (tid < 64) {
        float s = st[tid], sq = st[64 + tid];
        float m = s / (float)N, v = sq / (float)N - m * m;
        float a = g[tid] * rsqrtf(v + 1e-5f);
        sa[tid] = a; sc[tid] = be[tid] - a * m;
    }
    __syncthreads();
    int idx = blockIdx.x * 256 + tid;
    if (idx < N * 8) {
        int r = idx >> 3, c8 = idx & 7;
        uint4 raw = *(const uint4*)(y + (size_t)r * 64 + c8 * 8);
        unsigned int rw[4] = {raw.x, raw.y, raw.z, raw.w};
        float o[8];
        #pragma unroll
        for (int q = 0; q < 4; ++q) {
            int col = c8 * 8 + q * 2;
            o[q * 2 + 0] = fmaxf(fmaf(sa[col + 0], bf2f(rw[q] & 0xFFFFu), sc[col + 0]), 0.f);
            o[q * 2 + 1] = fmaxf(fmaf(sa[col + 1], bf2f(rw[q] >> 16), sc[col + 1]), 0.f);
        }
        float4 o0 = {o[0], o[1], o[2], o[3]}, o1 = {o[4], o[5], o[6], o[7]};
        *(float4*)(out + (size_t)r * 64 + c8 * 8) = o0;
        *(float4*)(out + (size_t)r * 64 + c8 * 8 + 4) = o1;
    }
}

extern "C" void kernel_launch(void* const* d_in, const int* in_sizes, int n_in,
                              void* d_out, int out_size, void* d_ws, size_t ws_size,
                              hipStream_t stream) {
    (void)n_in; (void)out_size; (void)ws_size;
    const float* x0 = (const float*)d_in[0];
    const float* x1 = (const float*)d_in[1];
    const float* x2 = (const float*)d_in[2];
    const int* up_index0 = (const int*)d_in[3];
    const int* up_index1 = (const int*)d_in[4];
    const int* bnd_src1  = (const int*)d_in[5];
    const int* bnd_dst1  = (const int*)d_in[6];
    const int* bnd_src2  = (const int*)d_in[7];
    const int* bnd_dst2  = (const int*)d_in[8];
    const float* up_W1 = (const float*)d_in[9];
    const float* up_b1 = (const float*)d_in[10];
    const float* up_g1 = (const float*)d_in[11];
    const float* up_be1= (const float*)d_in[12];
    const float* up_W2 = (const float*)d_in[13];
    const float* up_b2 = (const float*)d_in[14];
    const float* up_g2 = (const float*)d_in[15];
    const float* up_be2= (const float*)d_in[16];
    const float* bd_W1 = (const float*)d_in[17];
    const float* bd_b1 = (const float*)d_in[18];
    const float* bd_g1 = (const float*)d_in[19];
    const float* bd_be1= (const float*)d_in[20];
    const float* bd_W2 = (const float*)d_in[21];
    const float* bd_b2 = (const float*)d_in[22];
    const float* bd_g2 = (const float*)d_in[23];
    const float* bd_be2= (const float*)d_in[24];
    const float* cmb_W = (const float*)d_in[25];
    const float* cmb_b = (const float*)d_in[26];
    const float* cmb_g = (const float*)d_in[27];
    const float* cmb_be= (const float*)d_in[28];
    const float* epsP  = (const float*)d_in[29];

    const int EU0 = in_sizes[3] / 2, EU1 = in_sizes[4] / 2;
    const int EB1 = in_sizes[5],     EB2 = in_sizes[7];
    const int n0 = in_sizes[0] / 64, n1 = in_sizes[1] / 64, n2 = in_sizes[2] / 64;
    const int nMax02 = (n0 > n2) ? n0 : n2;

    float* outP = (float*)d_out;

    // ---- ws layout (all 16B-aligned) ----
    unsigned short* bufU = (unsigned short*)d_ws;              // n1*64 bf16
    unsigned short* bufB = bufU + (size_t)n1 * 64;             // max(n0,n2)*64 bf16
    float* stats = (float*)(bufB + (size_t)nMax02 * 64);       // 15*128 fp32
    int*   bsum  = (int*)(stats + 15 * 128);                   // 1024 ints
    unsigned short* wT = (unsigned short*)(bsum + 1024);       // 73728 bf16

    // Concatenated CSR storage in out2 region (dead until level-2 final apply)
    // curAll: n0 + n1 + n1 + n2 counters; esrcAll: EU0+EU1+EB1+EB2 indices
    const int NT  = n0 + 2 * n1 + n2;
    const int ETT = EU0 + EU1 + EB1 + EB2;
    const int oU0 = 0, oU1 = n0, oB1 = n0 + n1, oB2 = n0 + 2 * n1;
    const int eU0 = 0, eU1 = EU0, eB1 = EU0 + EU1, eB2 = EU0 + EU1 + EB1;
    int* curAll  = (int*)(outP + (size_t)(n0 + n1) * 64);
    int* esrcAll = curAll + NT;

    // level-1 bd intermediate lives in out1 region (dead until level-1 apply)
    unsigned short* hBd1 = (unsigned short*)(outP + (size_t)n0 * 64);

    hipMemsetAsync(stats, 0, 15 * 128 * sizeof(float), stream);
    wprep_k<<<15, 256, 0, stream>>>(up_W1, up_W2, bd_W1, bd_W2, cmb_W, wT);

    // ---- fused CSR build ----
    hipMemsetAsync(curAll, 0, (size_t)NT * sizeof(int), stream);
    hist_all_k<<<(ETT + 255) / 256, 256, 0, stream>>>(
        up_index0 + EU0, up_index1 + EU1, bnd_dst1, bnd_dst2,
        EU0, EU1, EB1, EB2, oU0, oU1, oB1, oB2, curAll);
    int nbScan = (NT + 2047) / 2048;
    scanA_k<<<nbScan, 256, 0, stream>>>(curAll, bsum, NT);
    scanB_k<<<1, 512, 0, stream>>>(bsum, nbScan);
    scanC_k<<<nbScan, 256, 0, stream>>>(curAll, bsum, NT);
    fill_all_k<<<(ETT + 255) / 256, 256, 0, stream>>>(
        up_index0, up_index0 + EU0, up_index1, up_index1 + EU1,
        bnd_src1, bnd_dst1, bnd_src2, bnd_dst2,
        EU0, EU1, EB1, EB2, oU0, oU1, oB1, oB2, curAll, esrcAll);

    auto S  = [&](int d, int i) { return stats + (size_t)(d * 5 + i) * 128; };
    auto WT = [&](int d, int j) { return wT + (size_t)d * 24576 + (j < 4 ? j * 4096 : 16384); };

    auto runLevel = [&](int d, const float* x, int N,
                        const int* curUp, int ebUp,
                        const int* curBd, int ebBd, const float* bdX,
                        unsigned short* hUp, unsigned short* hBd, float* outR) {
        dim3 gblk((N + 63) / 64);
        gemm_bn_k<<<gblk, 256, 0, stream>>>(0, curUp, esrcAll, ebUp, x, x, nullptr, nullptr,
            nullptr, nullptr, nullptr, nullptr, nullptr, nullptr,
            epsP, d, WT(d, 0), up_b1 + d * 64, hUp, S(d, 0), N);
        gemm_bn_k<<<gblk, 256, 0, stream>>>(1, nullptr, nullptr, 0, nullptr, nullptr, hUp, nullptr,
            S(d, 0), up_g1 + d * 64, up_be1 + d * 64, nullptr, nullptr, nullptr,
            nullptr, 0, WT(d, 1), up_b2 + d * 64, hUp, S(d, 1), N);
        gemm_bn_k<<<gblk, 256, 0, stream>>>(0, curBd, esrcAll, ebBd, bdX, x, nullptr, nullptr,
            nullptr, nullptr, nullptr, nullptr, nullptr, nullptr,
            epsP, d, WT(d, 2), bd_b1 + d * 64, hBd, S(d, 2), N);
        gemm_bn_k<<<gblk, 256, 0, stream>>>(1, nullptr, nullptr, 0, nullptr, nullptr, hBd, nullptr,
            S(d, 2), bd_g1 + d * 64, bd_be1 + d * 64, nullptr, nullptr, nullptr,
            nullptr, 0, WT(d, 3), bd_b2 + d * 64, hBd, S(d, 3), N);
        gemm_bn_k<<<gblk, 256, 0, stream>>>(2, nullptr, nullptr, 0, nullptr, nullptr, hUp, hBd,
            S(d, 1), up_g2 + d * 64, up_be2 + d * 64,
            S(d, 3), bd_g2 + d * 64, bd_be2 + d * 64,
            nullptr, 0, WT(d, 4), cmb_b + d * 64, hUp, S(d, 4), N);
        bn_relu_apply_k<<<(N * 8 + 255) / 256, 256, 0, stream>>>(
            hUp, S(d, 4), cmb_g + d * 64, cmb_be + d * 64, outR, N);
    };

    // level 0: up adjacency only
    runLevel(0, x0, n0, curAll + oU0, eU0, nullptr, 0, nullptr,
             bufU, bufB, outP);
    // level 1: up adjacency + node boundaries (boundary attr = x0)
    runLevel(1, x1, n1, curAll + oU1, eU1, curAll + oB1, eB1, x0,
             bufU, hBd1, outP + (size_t)n0 * 64);
    // level 2: edge boundaries only (boundary attr = x1)
    runLevel(2, x2, n2, nullptr, 0, curAll + oB2, eB2, x1,
             bufU, bufB, outP + (size_t)(n0 + n1) * 64);
}

// Round 3
// 1732.681 us; speedup vs baseline: 1.2561x; 1.2554x over previous
//
#include <hip/hip_runtime.h>
#include <cstdint>
#include <cstddef>

// ---------------------------------------------------------------------------
// SparseCINConv, MFMA edition.
// R3: (a) hist/fill scatter localized per-XCD: destination-row space split
//     into 8 ranges, range p handled by blocks with blockIdx&7==p (round-robin
//     XCD mapping) -> scatter window ~2MB per XCD L2, kills the 67B/4B HBM
//     write amplification seen in R2 (WRITE_SIZE 263MB for 15.6MB payload).
//     (b) level-parallel stage merge: the 3 levels are independent, so the
//     18 serial gemm/apply dispatches become K1(6 stage-1 segs), K2(6
//     stage-2), K3(3 cmb), apply(L2), apply(L0+L1) -- removes 12+ launch
//     drains and all small-dispatch tails.
// ---------------------------------------------------------------------------

using bfrag = __attribute__((ext_vector_type(8))) short;   // 8 bf16 (4 VGPRs)
using f32x4 = __attribute__((ext_vector_type(4))) float;   // 4 fp32 acc

__device__ __forceinline__ unsigned short f2bf(float f) {
    unsigned int u = __float_as_uint(f);
    u += 0x7FFFu + ((u >> 16) & 1u);          // RNE
    return (unsigned short)(u >> 16);
}
__device__ __forceinline__ float bf2f(unsigned int h) {
    return __uint_as_float(h << 16);
}

// ---------------- XCD-ranged CSR build (4 concatenated edge sets) -----------
// pass = blockIdx&7 ~ XCD id (round-robin dispatch); each pass owns row range
// [pass*W, pass*W+W) so its scatter targets stay resident in one XCD's L2.

__global__ __launch_bounds__(256) void hist_ranged_k(
    const int* __restrict__ d0, const int* __restrict__ d1,
    const int* __restrict__ d2, const int* __restrict__ d3,
    int E0, int E1, int E2, int E3,
    int o0, int o1, int o2, int o3,
    int* __restrict__ cnt, int NT)
{
    const int pass = blockIdx.x & 7;
    const int W = (NT + 7) >> 3;
    const int lo = pass * W;
    int hi = lo + W; if (hi > NT) hi = NT;
    const int ET = E0 + E1 + E2 + E3;
    const int nsub = gridDim.x >> 3;
    for (int e = (blockIdx.x >> 3) * 256 + threadIdx.x; e < ET; e += nsub * 256) {
        int g;
        if (e < E0) g = o0 + d0[e];
        else if (e < E0 + E1) g = o1 + d1[e - E0];
        else if (e < E0 + E1 + E2) g = o2 + d2[e - E0 - E1];
        else g = o3 + d3[e - E0 - E1 - E2];
        if (g >= lo && g < hi) atomicAdd(&cnt[g], 1);
    }
}

__global__ __launch_bounds__(256) void fill_ranged_k(
    const int* __restrict__ s0, const int* __restrict__ d0,
    const int* __restrict__ s1, const int* __restrict__ d1,
    const int* __restrict__ s2, const int* __restrict__ d2,
    const int* __restrict__ s3, const int* __restrict__ d3,
    int E0, int E1, int E2, int E3,
    int o0, int o1, int o2, int o3,
    int* __restrict__ cur, int* __restrict__ esrc, int NT)
{
    const int pass = blockIdx.x & 7;
    const int W = (NT + 7) >> 3;
    const int lo = pass * W;
    int hi = lo + W; if (hi > NT) hi = NT;
    const int ET = E0 + E1 + E2 + E3;
    const int nsub = gridDim.x >> 3;
    for (int e = (blockIdx.x >> 3) * 256 + threadIdx.x; e < ET; e += nsub * 256) {
        int g; const int* sp; int ei;
        if (e < E0) { g = o0 + d0[e]; sp = s0; ei = e; }
        else if (e < E0 + E1) { ei = e - E0; g = o1 + d1[ei]; sp = s1; }
        else if (e < E0 + E1 + E2) { ei = e - E0 - E1; g = o2 + d2[ei]; sp = s2; }
        else { ei = e - E0 - E1 - E2; g = o3 + d3[ei]; sp = s3; }
        if (g >= lo && g < hi) {
            int pos = atomicAdd(&cur[g], 1);
            esrc[pos] = sp[ei];
        }
    }
}

// 2048 elements / block (8 per thread) so one scanB level covers 1M counters.
__global__ __launch_bounds__(256) void scanA_k(int* __restrict__ a,
                                               int* __restrict__ bsum, int n) {
    __shared__ int ts[256];
    int tid = threadIdx.x;
    int base = blockIdx.x * 2048 + tid * 8;
    int v[8]; int s = 0;
    #pragma unroll
    for (int i = 0; i < 8; ++i) { v[i] = (base + i < n) ? a[base + i] : 0; s += v[i]; }
    ts[tid] = s;
    __syncthreads();
    for (int off = 1; off < 256; off <<= 1) {
        int t = (tid >= off) ? ts[tid - off] : 0;
        __syncthreads();
        ts[tid] += t;
        __syncthreads();
    }
    int run = ts[tid] - s;
    #pragma unroll
    for (int i = 0; i < 8; ++i) {
        if (base + i < n) { int o = v[i]; a[base + i] = run; run += o; }
    }
    if (tid == 255) bsum[blockIdx.x] = ts[255];
}

__global__ __launch_bounds__(512) void scanB_k(int* __restrict__ bsum, int nb) {
    __shared__ int ls[512];
    int tid = threadIdx.x;
    int v = (tid < nb) ? bsum[tid] : 0;
    ls[tid] = v;
    __syncthreads();
    for (int off = 1; off < 512; off <<= 1) {
        int t = (tid >= off) ? ls[tid - off] : 0;
        __syncthreads();
        ls[tid] += t;
        __syncthreads();
    }
    if (tid < nb) bsum[tid] = ls[tid] - v;
}

__global__ __launch_bounds__(256) void scanC_k(int* __restrict__ a,
                                               const int* __restrict__ bsum, int n) {
    int base = blockIdx.x * 2048 + threadIdx.x * 8;
    int add = bsum[blockIdx.x];
    #pragma unroll
    for (int i = 0; i < 8; ++i)
        if (base + i < n) a[base + i] += add;
}

// ---------------- weight prep: fp32 [K][64] -> bf16 transposed [64][K] -------

__global__ __launch_bounds__(256) void wprep_k(
    const float* __restrict__ upW1, const float* __restrict__ upW2,
    const float* __restrict__ bdW1, const float* __restrict__ bdW2,
    const float* __restrict__ cmbW, unsigned short* __restrict__ wT)
{
    int id = blockIdx.x;        // 0..14 = d*5 + j
    int d = id / 5, j = id % 5;
    const float* src; int K = 64;
    if (j == 0)      src = upW1 + (size_t)d * 4096;
    else if (j == 1) src = upW2 + (size_t)d * 4096;
    else if (j == 2) src = bdW1 + (size_t)d * 4096;
    else if (j == 3) src = bdW2 + (size_t)d * 4096;
    else           { src = cmbW + (size_t)d * 8192; K = 128; }
    unsigned short* dst = wT + (size_t)d * 24576 + (j < 4 ? j * 4096 : 16384);
    for (int e = threadIdx.x; e < K * 64; e += 256) {
        int k = e >> 6, n = e & 63;
        dst[n * K + k] = f2bf(src[e]);
    }
}

// ---------------- merged multi-segment MFMA GEMM + BN-stats ----------------
// mode 0: A = csr_gather(xs) + (1+eps)*xself   (fp32 in, K=64)
// mode 1: A = relu(bn(in0))                     (bf16 in, K=64)
// mode 2: A = concat(relu(bn(in0)),relu(bn(in1))) (bf16 in, K=128)
// out(bf16) = A @ W + bias ; ostats += {colsum, colsumsq} (fp32)

struct SegG {
    const int* cur;
    const float* xs; const float* xself;
    const unsigned short* in0; const unsigned short* in1;
    const float* st0; const float* g0; const float* be0;
    const float* st1; const float* g1; const float* be1;
    const unsigned short* wT; const float* bias;
    unsigned short* out; float* ostats;
    int N; int blk0; int eBase; int epsIdx;
};
struct GemmArgs { SegG s[6]; int nseg; const int* esrc; const float* epsP; };

__global__ __launch_bounds__(256) void gemm_bn_multi_k(int mode, GemmArgs A)
{
    __shared__ unsigned short sIn[64][72];  // +8 pad
    __shared__ unsigned short sW[64][72];   // W transposed [n][k]
    __shared__ float sCoef[4][64];
    __shared__ float sBias[64];
    __shared__ float sRedS[4][64];
    __shared__ float sRedQ[4][64];

    int si = 0;
    #pragma unroll
    for (int i = 1; i < 6; ++i)
        if (i < A.nseg && (int)blockIdx.x >= A.s[i].blk0) si = i;
    const SegG S = A.s[si];
    const int* esrc = A.esrc;

    const int tid = threadIdx.x;
    const int row0 = ((int)blockIdx.x - S.blk0) * 64;
    const int N = S.N;
    const float Nf = (float)N;

    if (tid < 64) {
        sBias[tid] = S.bias[tid];
        if (mode >= 1) {
            float s = S.st0[tid], sq = S.st0[64 + tid];
            float m = s / Nf, v = sq / Nf - m * m;
            float a = S.g0[tid] * rsqrtf(v + 1e-5f);
            sCoef[0][tid] = a; sCoef[1][tid] = S.be0[tid] - a * m;
        }
    } else if (tid < 128 && mode == 2) {
        int k = tid - 64;
        float s = S.st1[k], sq = S.st1[64 + k];
        float m = s / Nf, v = sq / Nf - m * m;
        float a = S.g1[k] * rsqrtf(v + 1e-5f);
        sCoef[2][k] = a; sCoef[3][k] = S.be1[k] - a * m;
    }
    const float sx = (mode == 0) ? (1.0f + A.epsP[S.epsIdx]) : 0.f;
    __syncthreads();

    f32x4 acc[4] = {};
    const int K = (mode == 2) ? 128 : 64;
    const int nch = (mode == 2) ? 2 : 1;
    const int wv = tid >> 6, l = tid & 63, l15 = l & 15, quad = l >> 4;

    for (int ch = 0; ch < nch; ++ch) {
        if (ch) __syncthreads();   // LDS reuse between chunks
        if (mode == 0) {
            // 16-lane group per 4 rows; index-vectorized gather, 4-wide MLP.
            const int grp = tid >> 4, lane = tid & 15;
            const int r0g = row0 + grp * 4;
            float ax[4], ay[4], az[4], aw[4];
            int beg[4], deg[4];
            #pragma unroll
            for (int rr = 0; rr < 4; ++rr) {
                int gr = r0g + rr;
                float4 xv = {0.f, 0.f, 0.f, 0.f};
                if (gr < N)
                    xv = *(const float4*)(S.xself + (size_t)gr * 64 + lane * 4);
                ax[rr] = sx * xv.x; ay[rr] = sx * xv.y;
                az[rr] = sx * xv.z; aw[rr] = sx * xv.w;
                int b = 0, d = 0;
                if (gr < N && S.cur) {
                    b = (gr == 0) ? S.eBase : S.cur[gr - 1];
                    d = S.cur[gr] - b;
                }
                beg[rr] = b; deg[rr] = d;
            }
            #pragma unroll
            for (int rr = 0; rr < 4; ++rr) {
                for (int base = 0; base < deg[rr]; base += 16) {
                    int take = deg[rr] - base; if (take > 16) take = 16;
                    int idxl = 0;
                    if (lane < take) idxl = esrc[beg[rr] + base + lane];
                    for (int j0 = 0; j0 < take; j0 += 4) {
                        float4 v0 = {0,0,0,0}, v1 = {0,0,0,0};
                        float4 v2 = {0,0,0,0}, v3 = {0,0,0,0};
                        int si2 = __shfl(idxl, j0, 16);
                        v0 = *(const float4*)(S.xs + (size_t)si2 * 64 + lane * 4);
                        if (j0 + 1 < take) {
                            si2 = __shfl(idxl, j0 + 1, 16);
                            v1 = *(const float4*)(S.xs + (size_t)si2 * 64 + lane * 4);
                        }
                        if (j0 + 2 < take) {
                            si2 = __shfl(idxl, j0 + 2, 16);
                            v2 = *(const float4*)(S.xs + (size_t)si2 * 64 + lane * 4);
                        }
                        if (j0 + 3 < take) {
                            si2 = __shfl(idxl, j0 + 3, 16);
                            v3 = *(const float4*)(S.xs + (size_t)si2 * 64 + lane * 4);
                        }
                        ax[rr] += (v0.x + v1.x) + (v2.x + v3.x);
                        ay[rr] += (v0.y + v1.y) + (v2.y + v3.y);
                        az[rr] += (v0.z + v1.z) + (v2.z + v3.z);
                        aw[rr] += (v0.w + v1.w) + (v2.w + v3.w);
                    }
                }
                ushort4 pk;
                pk.x = f2bf(ax[rr]); pk.y = f2bf(ay[rr]);
                pk.z = f2bf(az[rr]); pk.w = f2bf(aw[rr]);
                *(ushort4*)&sIn[grp * 4 + rr][lane * 4] = pk;
            }
        } else {
            const unsigned short* base = ch ? S.in1 : S.in0;
            const int ci = ch * 2;
            #pragma unroll
            for (int it = 0; it < 2; ++it) {
                int id = tid + it * 256;
                int r = id >> 3, c8 = id & 7;
                int gr = row0 + r;
                uint4 pk = {0u, 0u, 0u, 0u};
                if (gr < N) {
                    uint4 raw = *(const uint4*)(base + (size_t)gr * 64 + c8 * 8);
                    unsigned int rw[4] = {raw.x, raw.y, raw.z, raw.w};
                    unsigned int ow[4];
                    #pragma unroll
                    for (int q2 = 0; q2 < 4; ++q2) {
                        int col = c8 * 8 + q2 * 2;
                        float v0 = fmaxf(fmaf(sCoef[ci][col], bf2f(rw[q2] & 0xFFFFu),
                                              sCoef[ci + 1][col]), 0.f);
                        float v1 = fmaxf(fmaf(sCoef[ci][col + 1], bf2f(rw[q2] >> 16),
                                              sCoef[ci + 1][col + 1]), 0.f);
                        ow[q2] = (unsigned int)f2bf(v0) | ((unsigned int)f2bf(v1) << 16);
                    }
                    pk.x = ow[0]; pk.y = ow[1]; pk.z = ow[2]; pk.w = ow[3];
                }
                *(uint4*)&sIn[r][c8 * 8] = pk;
            }
        }
        #pragma unroll
        for (int it = 0; it < 2; ++it) {
            int id = tid + it * 256;
            int nr = id >> 3, c8 = id & 7;
            uint4 w = *(const uint4*)(S.wT + (size_t)nr * K + ch * 64 + c8 * 8);
            *(uint4*)&sW[nr][c8 * 8] = w;
        }
        __syncthreads();
        // A frag: A[m=lane&15][k=quad*8+j]; B frag: B[k=quad*8+j][n=lane&15]
        bfrag a0 = *(const bfrag*)&sIn[16 * wv + l15][quad * 8];
        bfrag a1 = *(const bfrag*)&sIn[16 * wv + l15][32 + quad * 8];
        #pragma unroll
        for (int c = 0; c < 4; ++c) {
            bfrag b0 = *(const bfrag*)&sW[16 * c + l15][quad * 8];
            bfrag b1 = *(const bfrag*)&sW[16 * c + l15][32 + quad * 8];
            acc[c] = __builtin_amdgcn_mfma_f32_16x16x32_bf16(a0, b0, acc[c], 0, 0, 0);
            acc[c] = __builtin_amdgcn_mfma_f32_16x16x32_bf16(a1, b1, acc[c], 0, 0, 0);
        }
    }

    // epilogue: bias, bf16 store, fp32 column stats
    // C/D layout: col = lane&15 (+16c), row = quad*4 + reg (+16*wv)
    float psv[4], pqv[4];
    #pragma unroll
    for (int c = 0; c < 4; ++c) {
        int col = 16 * c + l15;
        float b = sBias[col];
        float ps = 0.f, pq = 0.f;
        #pragma unroll
        for (int r = 0; r < 4; ++r) {
            int grow = row0 + 16 * wv + quad * 4 + r;
            if (grow < N) {
                float v = acc[c][r] + b;
                S.out[(size_t)grow * 64 + col] = f2bf(v);
                ps += v; pq += v * v;
            }
        }
        psv[c] = ps; pqv[c] = pq;
    }
    #pragma unroll
    for (int c = 0; c < 4; ++c) {
        float ps = psv[c], pq = pqv[c];
        ps += __shfl_xor(ps, 16, 64); pq += __shfl_xor(pq, 16, 64);
        ps += __shfl_xor(ps, 32, 64); pq += __shfl_xor(pq, 32, 64);
        if (l < 16) { sRedS[wv][16 * c + l] = ps; sRedQ[wv][16 * c + l] = pq; }
    }
    __syncthreads();
    if (tid < 64) {
        float s = sRedS[0][tid] + sRedS[1][tid] + sRedS[2][tid] + sRedS[3][tid];
        float q = sRedQ[0][tid] + sRedQ[1][tid] + sRedQ[2][tid] + sRedQ[3][tid];
        unsafeAtomicAdd(&S.ostats[tid], s);
        unsafeAtomicAdd(&S.ostats[64 + tid], q);
    }
}

// ---------------- merged final BN+ReLU apply ----------------

struct SegA {
    const unsigned short* in; const float* st; const float* g; const float* be;
    float* out; int N; int blk0;
};
struct ApplyArgs { SegA s[2]; int nseg; };

__global__ __launch_bounds__(256) void bn_relu_apply_multi_k(ApplyArgs A)
{
    __shared__ float sa[64], sc[64];
    int si = 0;
    if (A.nseg > 1 && (int)blockIdx.x >= A.s[1].blk0) si = 1;
    const SegA S = A.s[si];
    int tid = threadIdx.x;
    if (tid < 64) {
        float s = S.st[tid], sq = S.st[64 + tid];
        float m = s / (float)S.N, v = sq / (float)S.N - m * m;
        float a = S.g[tid] * rsqrtf(v + 1e-5f);
        sa[tid] = a; sc[tid] = S.be[tid] - a * m;
    }
    __syncthreads();
    int idx = ((int)blockIdx.x - S.blk0) * 256 + tid;
    if (idx < S.N * 8) {
        int r = idx >> 3, c8 = idx & 7;
        uint4 raw = *(const uint4*)(S.in + (size_t)r * 64 + c8 * 8);
        unsigned int rw[4] = {raw.x, raw.y, raw.z, raw.w};
        float o[8];
        #pragma unroll
        for (int q = 0; q < 4; ++q) {
            int col = c8 * 8 + q * 2;
            o[q * 2 + 0] = fmaxf(fmaf(sa[col + 0], bf2f(rw[q] & 0xFFFFu), sc[col + 0]), 0.f);
            o[q * 2 + 1] = fmaxf(fmaf(sa[col + 1], bf2f(rw[q] >> 16), sc[col + 1]), 0.f);
        }
        float4 o0 = {o[0], o[1], o[2], o[3]}, o1 = {o[4], o[5], o[6], o[7]};
        *(float4*)(S.out + (size_t)r * 64 + c8 * 8) = o0;
        *(float4*)(S.out + (size_t)r * 64 + c8 * 8 + 4) = o1;
    }
}

extern "C" void kernel_launch(void* const* d_in, const int* in_sizes, int n_in,
                              void* d_out, int out_size, void* d_ws, size_t ws_size,
                              hipStream_t stream) {
    (void)n_in; (void)out_size; (void)ws_size;
    const float* x0 = (const float*)d_in[0];
    const float* x1 = (const float*)d_in[1];
    const float* x2 = (const float*)d_in[2];
    const int* up_index0 = (const int*)d_in[3];
    const int* up_index1 = (const int*)d_in[4];
    const int* bnd_src1  = (const int*)d_in[5];
    const int* bnd_dst1  = (const int*)d_in[6];
    const int* bnd_src2  = (const int*)d_in[7];
    const int* bnd_dst2  = (const int*)d_in[8];
    const float* up_W1 = (const float*)d_in[9];
    const float* up_b1 = (const float*)d_in[10];
    const float* up_g1 = (const float*)d_in[11];
    const float* up_be1= (const float*)d_in[12];
    const float* up_W2 = (const float*)d_in[13];
    const float* up_b2 = (const float*)d_in[14];
    const float* up_g2 = (const float*)d_in[15];
    const float* up_be2= (const float*)d_in[16];
    const float* bd_W1 = (const float*)d_in[17];
    const float* bd_b1 = (const float*)d_in[18];
    const float* bd_g1 = (const float*)d_in[19];
    const float* bd_be1= (const float*)d_in[20];
    const float* bd_W2 = (const float*)d_in[21];
    const float* bd_b2 = (const float*)d_in[22];
    const float* bd_g2 = (const float*)d_in[23];
    const float* bd_be2= (const float*)d_in[24];
    const float* cmb_W = (const float*)d_in[25];
    const float* cmb_b = (const float*)d_in[26];
    const float* cmb_g = (const float*)d_in[27];
    const float* cmb_be= (const float*)d_in[28];
    const float* epsP  = (const float*)d_in[29];

    const int EU0 = in_sizes[3] / 2, EU1 = in_sizes[4] / 2;
    const int EB1 = in_sizes[5],     EB2 = in_sizes[7];
    const int n0 = in_sizes[0] / 64, n1 = in_sizes[1] / 64, n2 = in_sizes[2] / 64;
    const int nMax02 = (n0 > n2) ? n0 : n2;

    float* outP = (float*)d_out;

    // ---- ws layout (all 16B-aligned) ----
    unsigned short* bufU = (unsigned short*)d_ws;              // n1*64 bf16  (hU1/c1)
    unsigned short* bufB = bufU + (size_t)n1 * 64;             // nMax02*64 bf16 (hU0/c0)
    float* stats = (float*)(bufB + (size_t)nMax02 * 64);       // 15*128 fp32
    int*   bsum  = (int*)(stats + 15 * 128);                   // 1024 ints
    unsigned short* wT = (unsigned short*)(bsum + 1024);       // 73728 bf16

    // Concatenated CSR storage in out2 region (dead until apply(L2))
    const int NT  = n0 + 2 * n1 + n2;
    const int ETT = EU0 + EU1 + EB1 + EB2;
    const int oU0 = 0, oU1 = n0, oB1 = n0 + n1, oB2 = n0 + 2 * n1;
    const int eU0 = 0, eU1 = EU0, eB1 = EU0 + EU1, eB2 = EU0 + EU1 + EB1;
    int* curAll  = (int*)(outP + (size_t)(n0 + n1) * 64);
    int* esrcAll = curAll + NT;

    // intermediates (bf16, N*64 each):
    unsigned short* hU0 = bufB;                                            // ws
    unsigned short* hB0 = (unsigned short*)outP;                           // out0 lower half
    unsigned short* hU2 = (unsigned short*)outP + (size_t)n0 * 64;         // out0 upper half
    unsigned short* hU1 = bufU;                                            // ws
    unsigned short* hB1 = (unsigned short*)(outP + (size_t)n0 * 64);       // out1 lower half
    unsigned short* hB2 = (unsigned short*)(outP + (size_t)n0 * 64) + (size_t)n1 * 64; // out1 upper

    hipMemsetAsync(stats, 0, 15 * 128 * sizeof(float), stream);
    wprep_k<<<15, 256, 0, stream>>>(up_W1, up_W2, bd_W1, bd_W2, cmb_W, wT);

    // ---- XCD-ranged CSR build ----
    hipMemsetAsync(curAll, 0, (size_t)NT * sizeof(int), stream);
    hist_ranged_k<<<2048, 256, 0, stream>>>(
        up_index0 + EU0, up_index1 + EU1, bnd_dst1, bnd_dst2,
        EU0, EU1, EB1, EB2, oU0, oU1, oB1, oB2, curAll, NT);
    int nbScan = (NT + 2047) / 2048;
    scanA_k<<<nbScan, 256, 0, stream>>>(curAll, bsum, NT);
    scanB_k<<<1, 512, 0, stream>>>(bsum, nbScan);
    scanC_k<<<nbScan, 256, 0, stream>>>(curAll, bsum, NT);
    fill_ranged_k<<<2048, 256, 0, stream>>>(
        up_index0, up_index0 + EU0, up_index1, up_index1 + EU1,
        bnd_src1, bnd_dst1, bnd_src2, bnd_dst2,
        EU0, EU1, EB1, EB2, oU0, oU1, oB1, oB2, curAll, esrcAll, NT);

    auto S  = [&](int d, int i) { return stats + (size_t)(d * 5 + i) * 128; };
    auto WTf = [&](int d, int j) { return wT + (size_t)d * 24576 + (j < 4 ? j * 4096 : 16384); };

    const int nb0 = (n0 + 63) / 64, nb1 = (n1 + 63) / 64, nb2 = (n2 + 63) / 64;

    // ---- K1: all 6 stage-1 GEMMs (mode 0) ----
    {
        GemmArgs A{}; A.nseg = 6; A.esrc = esrcAll; A.epsP = epsP;
        auto& s = A.s;
        // L0 up (gather x0)
        s[0] = { curAll + oU0, x0, x0, nullptr, nullptr,
                 nullptr, nullptr, nullptr, nullptr, nullptr, nullptr,
                 WTf(0,0), up_b1 + 0, hU0, S(0,0), n0, 0, eU0, 0 };
        // L0 bd (no gather)
        s[1] = { nullptr, nullptr, x0, nullptr, nullptr,
                 nullptr, nullptr, nullptr, nullptr, nullptr, nullptr,
                 WTf(0,2), bd_b1 + 0, hB0, S(0,2), n0, nb0, 0, 0 };
        // L1 up (gather x1)
        s[2] = { curAll + oU1, x1, x1, nullptr, nullptr,
                 nullptr, nullptr, nullptr, nullptr, nullptr, nullptr,
                 WTf(1,0), up_b1 + 64, hU1, S(1,0), n1, 2*nb0, eU1, 1 };
        // L1 bd (gather x0)
        s[3] = { curAll + oB1, x0, x1, nullptr, nullptr,
                 nullptr, nullptr, nullptr, nullptr, nullptr, nullptr,
                 WTf(1,2), bd_b1 + 64, hB1, S(1,2), n1, 2*nb0 + nb1, eB1, 1 };
        // L2 up (no gather)
        s[4] = { nullptr, nullptr, x2, nullptr, nullptr,
                 nullptr, nullptr, nullptr, nullptr, nullptr, nullptr,
                 WTf(2,0), up_b1 + 128, hU2, S(2,0), n2, 2*nb0 + 2*nb1, 0, 2 };
        // L2 bd (gather x1)
        s[5] = { curAll + oB2, x1, x2, nullptr, nullptr,
                 nullptr, nullptr, nullptr, nullptr, nullptr, nullptr,
                 WTf(2,2), bd_b1 + 128, hB2, S(2,2), n2, 2*nb0 + 2*nb1 + nb2, eB2, 2 };
        gemm_bn_multi_k<<<2*nb0 + 2*nb1 + 2*nb2, 256, 0, stream>>>(0, A);
    }

    // ---- K2: all 6 stage-2 GEMMs (mode 1, in-place) ----
    {
        GemmArgs A{}; A.nseg = 6; A.esrc = nullptr; A.epsP = epsP;
        auto& s = A.s;
        s[0] = { nullptr, nullptr, nullptr, hU0, nullptr,
                 S(0,0), up_g1 + 0, up_be1 + 0, nullptr, nullptr, nullptr,
                 WTf(0,1), up_b2 + 0, hU0, S(0,1), n0, 0, 0, 0 };
        s[1] = { nullptr, nullptr, nullptr, hB0, nullptr,
                 S(0,2), bd_g1 + 0, bd_be1 + 0, nullptr, nullptr, nullptr,
                 WTf(0,3), bd_b2 + 0, hB0, S(0,3), n0, nb0, 0, 0 };
        s[2] = { nullptr, nullptr, nullptr, hU1, nullptr,
                 S(1,0), up_g1 + 64, up_be1 + 64, nullptr, nullptr, nullptr,
                 WTf(1,1), up_b2 + 64, hU1, S(1,1), n1, 2*nb0, 0, 0 };
        s[3] = { nullptr, nullptr, nullptr, hB1, nullptr,
                 S(1,2), bd_g1 + 64, bd_be1 + 64, nullptr, nullptr, nullptr,
                 WTf(1,3), bd_b2 + 64, hB1, S(1,3), n1, 2*nb0 + nb1, 0, 0 };
        s[4] = { nullptr, nullptr, nullptr, hU2, nullptr,
                 S(2,0), up_g1 + 128, up_be1 + 128, nullptr, nullptr, nullptr,
                 WTf(2,1), up_b2 + 128, hU2, S(2,1), n2, 2*nb0 + 2*nb1, 0, 0 };
        s[5] = { nullptr, nullptr, nullptr, hB2, nullptr,
                 S(2,2), bd_g1 + 128, bd_be1 + 128, nullptr, nullptr, nullptr,
                 WTf(2,3), bd_b2 + 128, hB2, S(2,3), n2, 2*nb0 + 2*nb1 + nb2, 0, 0 };
        gemm_bn_multi_k<<<2*nb0 + 2*nb1 + 2*nb2, 256, 0, stream>>>(1, A);
    }

    // ---- K3: 3 cmb GEMMs (mode 2, out in-place over hU) ----
    {
        GemmArgs A{}; A.nseg = 3; A.esrc = nullptr; A.epsP = epsP;
        auto& s = A.s;
        s[0] = { nullptr, nullptr, nullptr, hU0, hB0,
                 S(0,1), up_g2 + 0, up_be2 + 0, S(0,3), bd_g2 + 0, bd_be2 + 0,
                 WTf(0,4), cmb_b + 0, hU0, S(0,4), n0, 0, 0, 0 };
        s[1] = { nullptr, nullptr, nullptr, hU1, hB1,
                 S(1,1), up_g2 + 64, up_be2 + 64, S(1,3), bd_g2 + 64, bd_be2 + 64,
                 WTf(1,4), cmb_b + 64, hU1, S(1,4), n1, nb0, 0, 0 };
        s[2] = { nullptr, nullptr, nullptr, hU2, hB2,
                 S(2,1), up_g2 + 128, up_be2 + 128, S(2,3), bd_g2 + 128, bd_be2 + 128,
                 WTf(2,4), cmb_b + 128, hU2, S(2,4), n2, nb0 + nb1, 0, 0 };
        gemm_bn_multi_k<<<nb0 + nb1 + nb2, 256, 0, stream>>>(2, A);
    }

    // ---- applies: L2 first (c_L2 lives in out0 upper, which apply(L0) kills) ----
    {
        ApplyArgs A{}; A.nseg = 1;
        A.s[0] = { hU2, S(2,4), cmb_g + 128, cmb_be + 128,
                   outP + (size_t)(n0 + n1) * 64, n2, 0 };
        bn_relu_apply_multi_k<<<(n2 * 8 + 255) / 256, 256, 0, stream>>>(A);
    }
    {
        ApplyArgs A{}; A.nseg = 2;
        int ab0 = (n0 * 8 + 255) / 256;
        A.s[0] = { hU0, S(0,4), cmb_g + 0, cmb_be + 0, outP, n0, 0 };
        A.s[1] = { hU1, S(1,4), cmb_g + 64, cmb_be + 64,
                   outP + (size_t)n0 * 64, n1, ab0 };
        bn_relu_apply_multi_k<<<ab0 + (n1 * 8 + 255) / 256, 256, 0, stream>>>(A);
    }
}

// Round 4
// 1589.679 us; speedup vs baseline: 1.3691x; 1.0900x over previous
//
#include <hip/hip_runtime.h>
#include <cstdint>
#include <cstddef>

// ---------------------------------------------------------------------------
// SparseCINConv, MFMA edition.
// R4: (a) K1 up/bd branch pair fused per level (gemm_pair_k): xself read once,
//     both gathers from registers, two GEMM passes per block. (b) K1 + apply
//     outputs via LDS-coalesced __builtin_nontemporal_store (no L2/L3
//     allocation) so the 153MB of intermediate writes stop evicting the
//     gather tables (x0 25.6MB / x1 102MB both fit in 256MB L3; R3 showed
//     ~280MB of gather L3 misses caused by write-stream churn).
// ---------------------------------------------------------------------------

using bfrag = __attribute__((ext_vector_type(8))) short;   // 8 bf16 (4 VGPRs)
using f32x4 = __attribute__((ext_vector_type(4))) float;   // 4 fp32 acc
using u4v   = __attribute__((ext_vector_type(4))) unsigned int;
using f4v   = __attribute__((ext_vector_type(4))) float;

__device__ __forceinline__ unsigned short f2bf(float f) {
    unsigned int u = __float_as_uint(f);
    u += 0x7FFFu + ((u >> 16) & 1u);          // RNE
    return (unsigned short)(u >> 16);
}
__device__ __forceinline__ float bf2f(unsigned int h) {
    return __uint_as_float(h << 16);
}

// ---------------- XCD-ranged CSR build (4 concatenated edge sets) -----------

__global__ __launch_bounds__(256) void hist_ranged_k(
    const int* __restrict__ d0, const int* __restrict__ d1,
    const int* __restrict__ d2, const int* __restrict__ d3,
    int E0, int E1, int E2, int E3,
    int o0, int o1, int o2, int o3,
    int* __restrict__ cnt, int NT)
{
    const int pass = blockIdx.x & 7;
    const int W = (NT + 7) >> 3;
    const int lo = pass * W;
    int hi = lo + W; if (hi > NT) hi = NT;
    const int ET = E0 + E1 + E2 + E3;
    const int nsub = gridDim.x >> 3;
    for (int e = (blockIdx.x >> 3) * 256 + threadIdx.x; e < ET; e += nsub * 256) {
        int g;
        if (e < E0) g = o0 + d0[e];
        else if (e < E0 + E1) g = o1 + d1[e - E0];
        else if (e < E0 + E1 + E2) g = o2 + d2[e - E0 - E1];
        else g = o3 + d3[e - E0 - E1 - E2];
        if (g >= lo && g < hi) atomicAdd(&cnt[g], 1);
    }
}

__global__ __launch_bounds__(256) void fill_ranged_k(
    const int* __restrict__ s0, const int* __restrict__ d0,
    const int* __restrict__ s1, const int* __restrict__ d1,
    const int* __restrict__ s2, const int* __restrict__ d2,
    const int* __restrict__ s3, const int* __restrict__ d3,
    int E0, int E1, int E2, int E3,
    int o0, int o1, int o2, int o3,
    int* __restrict__ cur, int* __restrict__ esrc, int NT)
{
    const int pass = blockIdx.x & 7;
    const int W = (NT + 7) >> 3;
    const int lo = pass * W;
    int hi = lo + W; if (hi > NT) hi = NT;
    const int ET = E0 + E1 + E2 + E3;
    const int nsub = gridDim.x >> 3;
    for (int e = (blockIdx.x >> 3) * 256 + threadIdx.x; e < ET; e += nsub * 256) {
        int g; const int* sp; int ei;
        if (e < E0) { g = o0 + d0[e]; sp = s0; ei = e; }
        else if (e < E0 + E1) { ei = e - E0; g = o1 + d1[ei]; sp = s1; }
        else if (e < E0 + E1 + E2) { ei = e - E0 - E1; g = o2 + d2[ei]; sp = s2; }
        else { ei = e - E0 - E1 - E2; g = o3 + d3[ei]; sp = s3; }
        if (g >= lo && g < hi) {
            int pos = atomicAdd(&cur[g], 1);
            esrc[pos] = sp[ei];
        }
    }
}

// 2048 elements / block (8 per thread) so one scanB level covers 1M counters.
__global__ __launch_bounds__(256) void scanA_k(int* __restrict__ a,
                                               int* __restrict__ bsum, int n) {
    __shared__ int ts[256];
    int tid = threadIdx.x;
    int base = blockIdx.x * 2048 + tid * 8;
    int v[8]; int s = 0;
    #pragma unroll
    for (int i = 0; i < 8; ++i) { v[i] = (base + i < n) ? a[base + i] : 0; s += v[i]; }
    ts[tid] = s;
    __syncthreads();
    for (int off = 1; off < 256; off <<= 1) {
        int t = (tid >= off) ? ts[tid - off] : 0;
        __syncthreads();
        ts[tid] += t;
        __syncthreads();
    }
    int run = ts[tid] - s;
    #pragma unroll
    for (int i = 0; i < 8; ++i) {
        if (base + i < n) { int o = v[i]; a[base + i] = run; run += o; }
    }
    if (tid == 255) bsum[blockIdx.x] = ts[255];
}

__global__ __launch_bounds__(512) void scanB_k(int* __restrict__ bsum, int nb) {
    __shared__ int ls[512];
    int tid = threadIdx.x;
    int v = (tid < nb) ? bsum[tid] : 0;
    ls[tid] = v;
    __syncthreads();
    for (int off = 1; off < 512; off <<= 1) {
        int t = (tid >= off) ? ls[tid - off] : 0;
        __syncthreads();
        ls[tid] += t;
        __syncthreads();
    }
    if (tid < nb) bsum[tid] = ls[tid] - v;
}

__global__ __launch_bounds__(256) void scanC_k(int* __restrict__ a,
                                               const int* __restrict__ bsum, int n) {
    int base = blockIdx.x * 2048 + threadIdx.x * 8;
    int add = bsum[blockIdx.x];
    #pragma unroll
    for (int i = 0; i < 8; ++i)
        if (base + i < n) a[base + i] += add;
}

// ---------------- weight prep: fp32 [K][64] -> bf16 transposed [64][K] -------

__global__ __launch_bounds__(256) void wprep_k(
    const float* __restrict__ upW1, const float* __restrict__ upW2,
    const float* __restrict__ bdW1, const float* __restrict__ bdW2,
    const float* __restrict__ cmbW, unsigned short* __restrict__ wT)
{
    int id = blockIdx.x;        // 0..14 = d*5 + j
    int d = id / 5, j = id % 5;
    const float* src; int K = 64;
    if (j == 0)      src = upW1 + (size_t)d * 4096;
    else if (j == 1) src = upW2 + (size_t)d * 4096;
    else if (j == 2) src = bdW1 + (size_t)d * 4096;
    else if (j == 3) src = bdW2 + (size_t)d * 4096;
    else           { src = cmbW + (size_t)d * 8192; K = 128; }
    unsigned short* dst = wT + (size_t)d * 24576 + (j < 4 ? j * 4096 : 16384);
    for (int e = threadIdx.x; e < K * 64; e += 256) {
        int k = e >> 6, n = e & 63;
        dst[n * K + k] = f2bf(src[e]);
    }
}

// ---------------- K1: fused up+bd stage-1 GEMM pair per level ----------------
// Per block (64 rows of level d): z=(1+eps)x staged once from registers,
// gather-sum both branches into regs, then 2x {LDS stage, MFMA, epilogue}.
// Outputs via LDS-coalesced NT stores (no cache allocation).

struct SegP {
    const int* curU; const int* curB;
    const float* xsU; const float* xsB;
    const float* xself;
    const unsigned short* wTU; const unsigned short* wTB;
    const float* biasU; const float* biasB;
    unsigned short* outU; unsigned short* outB;
    float* statsU; float* statsB;
    int N; int blk0; int eBaseU; int eBaseB; int epsIdx;
};
struct PairArgs { SegP s[3]; const int* esrc; const float* epsP; };

__global__ __launch_bounds__(256) void gemm_pair_k(PairArgs A)
{
    __shared__ unsigned short sIn[64][72];
    __shared__ unsigned short sW[64][72];
    __shared__ float sBias[64];
    __shared__ float sRedS[4][64];
    __shared__ float sRedQ[4][64];

    int si = 0;
    if ((int)blockIdx.x >= A.s[1].blk0) si = 1;
    if ((int)blockIdx.x >= A.s[2].blk0) si = 2;
    const SegP S = A.s[si];
    const int* esrc = A.esrc;

    const int tid = threadIdx.x;
    const int row0 = ((int)blockIdx.x - S.blk0) * 64;
    const int N = S.N;
    const float sx = 1.0f + A.epsP[S.epsIdx];

    const int wv = tid >> 6, l = tid & 63, l15 = l & 15, quad = l >> 4;
    const int grp = tid >> 4, lane = tid & 15;
    const int r0g = row0 + grp * 4;

    // ---- gather phase: both branches in registers ----
    float axU[4], ayU[4], azU[4], awU[4];
    float axB[4], ayB[4], azB[4], awB[4];
    #pragma unroll
    for (int rr = 0; rr < 4; ++rr) {
        int gr = r0g + rr;
        float4 xv = {0.f, 0.f, 0.f, 0.f};
        if (gr < N)
            xv = *(const float4*)(S.xself + (size_t)gr * 64 + lane * 4);
        axU[rr] = sx * xv.x; ayU[rr] = sx * xv.y;
        azU[rr] = sx * xv.z; awU[rr] = sx * xv.w;
        axB[rr] = axU[rr]; ayB[rr] = ayU[rr];
        azB[rr] = azU[rr]; awB[rr] = awU[rr];
    }

    auto gatherAcc = [&](const int* cur, int eBase, const float* xs,
                         float (&ax)[4], float (&ay)[4], float (&az)[4],
                         float (&aw)[4]) {
        if (!cur) return;
        int beg[4], deg[4];
        #pragma unroll
        for (int rr = 0; rr < 4; ++rr) {
            int gr = r0g + rr; int b = 0, d = 0;
            if (gr < N) {
                b = (gr == 0) ? eBase : cur[gr - 1];
                d = cur[gr] - b;
            }
            beg[rr] = b; deg[rr] = d;
        }
        #pragma unroll
        for (int rr = 0; rr < 4; ++rr) {
            for (int base = 0; base < deg[rr]; base += 16) {
                int take = deg[rr] - base; if (take > 16) take = 16;
                int idxl = 0;
                if (lane < take) idxl = esrc[beg[rr] + base + lane];
                for (int j0 = 0; j0 < take; j0 += 4) {
                    float4 v0 = {0,0,0,0}, v1 = {0,0,0,0};
                    float4 v2 = {0,0,0,0}, v3 = {0,0,0,0};
                    int si2 = __shfl(idxl, j0, 16);
                    v0 = *(const float4*)(xs + (size_t)si2 * 64 + lane * 4);
                    if (j0 + 1 < take) {
                        si2 = __shfl(idxl, j0 + 1, 16);
                        v1 = *(const float4*)(xs + (size_t)si2 * 64 + lane * 4);
                    }
                    if (j0 + 2 < take) {
                        si2 = __shfl(idxl, j0 + 2, 16);
                        v2 = *(const float4*)(xs + (size_t)si2 * 64 + lane * 4);
                    }
                    if (j0 + 3 < take) {
                        si2 = __shfl(idxl, j0 + 3, 16);
                        v3 = *(const float4*)(xs + (size_t)si2 * 64 + lane * 4);
                    }
                    ax[rr] += (v0.x + v1.x) + (v2.x + v3.x);
                    ay[rr] += (v0.y + v1.y) + (v2.y + v3.y);
                    az[rr] += (v0.z + v1.z) + (v2.z + v3.z);
                    aw[rr] += (v0.w + v1.w) + (v2.w + v3.w);
                }
            }
        }
    };
    gatherAcc(S.curU, S.eBaseU, S.xsU, axU, ayU, azU, awU);
    gatherAcc(S.curB, S.eBaseB, S.xsB, axB, ayB, azB, awB);

    // ---- two GEMM+epilogue passes over shared LDS ----
    #pragma unroll
    for (int br = 0; br < 2; ++br) {
        if (br) __syncthreads();    // B4: prev branch's NT-out reads of sIn done
        const unsigned short* wTp = br ? S.wTB : S.wTU;
        const float* biasp = br ? S.biasB : S.biasU;
        unsigned short* outp = br ? S.outB : S.outU;
        float* statsp = br ? S.statsB : S.statsU;

        if (tid < 64) sBias[tid] = biasp[tid];
        {   // stage A from gather regs
            ushort4 pk;
            #pragma unroll
            for (int rr = 0; rr < 4; ++rr) {
                float x_ = br ? axB[rr] : axU[rr];
                float y_ = br ? ayB[rr] : ayU[rr];
                float z_ = br ? azB[rr] : azU[rr];
                float w_ = br ? awB[rr] : awU[rr];
                pk.x = f2bf(x_); pk.y = f2bf(y_);
                pk.z = f2bf(z_); pk.w = f2bf(w_);
                *(ushort4*)&sIn[grp * 4 + rr][lane * 4] = pk;
            }
        }
        #pragma unroll
        for (int it = 0; it < 2; ++it) {
            int id = tid + it * 256;
            int nr = id >> 3, c8 = id & 7;
            uint4 w = *(const uint4*)(wTp + (size_t)nr * 64 + c8 * 8);
            *(uint4*)&sW[nr][c8 * 8] = w;
        }
        __syncthreads();            // B1: staging visible

        bfrag a0 = *(const bfrag*)&sIn[16 * wv + l15][quad * 8];
        bfrag a1 = *(const bfrag*)&sIn[16 * wv + l15][32 + quad * 8];
        f32x4 acc[4] = {};
        #pragma unroll
        for (int c = 0; c < 4; ++c) {
            bfrag b0 = *(const bfrag*)&sW[16 * c + l15][quad * 8];
            bfrag b1 = *(const bfrag*)&sW[16 * c + l15][32 + quad * 8];
            acc[c] = __builtin_amdgcn_mfma_f32_16x16x32_bf16(a0, b0, acc[c], 0, 0, 0);
            acc[c] = __builtin_amdgcn_mfma_f32_16x16x32_bf16(a1, b1, acc[c], 0, 0, 0);
        }
        __syncthreads();            // B2: all fragment reads done, sIn reusable

        // C-tile -> sIn (bf16) + column partial stats
        float psv[4], pqv[4];
        #pragma unroll
        for (int c = 0; c < 4; ++c) {
            int col = 16 * c + l15;
            float b = sBias[col];
            float ps = 0.f, pq = 0.f;
            #pragma unroll
            for (int r4 = 0; r4 < 4; ++r4) {
                int lr = 16 * wv + quad * 4 + r4;
                float v = acc[c][r4] + b;
                sIn[lr][col] = f2bf(v);
                if (row0 + lr < N) { ps += v; pq += v * v; }
            }
            psv[c] = ps; pqv[c] = pq;
        }
        #pragma unroll
        for (int c = 0; c < 4; ++c) {
            float ps = psv[c], pq = pqv[c];
            ps += __shfl_xor(ps, 16, 64); pq += __shfl_xor(pq, 16, 64);
            ps += __shfl_xor(ps, 32, 64); pq += __shfl_xor(pq, 32, 64);
            if (l < 16) { sRedS[wv][16 * c + l] = ps; sRedQ[wv][16 * c + l] = pq; }
        }
        __syncthreads();            // B3: C-tile + sRed visible

        // coalesced NT store: 8 lanes/row, rows contiguous -> 1KB/wave-instr
        #pragma unroll
        for (int it = 0; it < 2; ++it) {
            int id = tid + it * 256;
            int r = id >> 3, c8 = id & 7;
            if (row0 + r < N) {
                u4v w = *(const u4v*)&sIn[r][c8 * 8];
                __builtin_nontemporal_store(
                    w, (u4v*)(outp + (size_t)(row0 + r) * 64 + c8 * 8));
            }
        }
        if (tid < 64) {
            float s = sRedS[0][tid] + sRedS[1][tid] + sRedS[2][tid] + sRedS[3][tid];
            float q = sRedQ[0][tid] + sRedQ[1][tid] + sRedQ[2][tid] + sRedQ[3][tid];
            unsafeAtomicAdd(&statsp[tid], s);
            unsafeAtomicAdd(&statsp[64 + tid], q);
        }
    }
}

// ---------------- merged multi-segment MFMA GEMM + BN-stats (modes 1,2) -----
// mode 1: A = relu(bn(in0))                     (bf16 in, K=64)
// mode 2: A = concat(relu(bn(in0)),relu(bn(in1))) (bf16 in, K=128)

struct SegG {
    const unsigned short* in0; const unsigned short* in1;
    const float* st0; const float* g0; const float* be0;
    const float* st1; const float* g1; const float* be1;
    const unsigned short* wT; const float* bias;
    unsigned short* out; float* ostats;
    int N; int blk0;
};
struct GemmArgs { SegG s[6]; int nseg; };

__global__ __launch_bounds__(256) void gemm_bn_multi_k(int mode, GemmArgs A)
{
    __shared__ unsigned short sIn[64][72];
    __shared__ unsigned short sW[64][72];
    __shared__ float sCoef[4][64];
    __shared__ float sBias[64];
    __shared__ float sRedS[4][64];
    __shared__ float sRedQ[4][64];

    int si = 0;
    #pragma unroll
    for (int i = 1; i < 6; ++i)
        if (i < A.nseg && (int)blockIdx.x >= A.s[i].blk0) si = i;
    const SegG S = A.s[si];

    const int tid = threadIdx.x;
    const int row0 = ((int)blockIdx.x - S.blk0) * 64;
    const int N = S.N;
    const float Nf = (float)N;

    if (tid < 64) {
        sBias[tid] = S.bias[tid];
        float s = S.st0[tid], sq = S.st0[64 + tid];
        float m = s / Nf, v = sq / Nf - m * m;
        float a = S.g0[tid] * rsqrtf(v + 1e-5f);
        sCoef[0][tid] = a; sCoef[1][tid] = S.be0[tid] - a * m;
    } else if (tid < 128 && mode == 2) {
        int k = tid - 64;
        float s = S.st1[k], sq = S.st1[64 + k];
        float m = s / Nf, v = sq / Nf - m * m;
        float a = S.g1[k] * rsqrtf(v + 1e-5f);
        sCoef[2][k] = a; sCoef[3][k] = S.be1[k] - a * m;
    }
    __syncthreads();

    f32x4 acc[4] = {};
    const int K = (mode == 2) ? 128 : 64;
    const int nch = (mode == 2) ? 2 : 1;
    const int wv = tid >> 6, l = tid & 63, l15 = l & 15, quad = l >> 4;

    for (int ch = 0; ch < nch; ++ch) {
        if (ch) __syncthreads();   // LDS reuse between chunks
        const unsigned short* base = ch ? S.in1 : S.in0;
        const int ci = ch * 2;
        #pragma unroll
        for (int it = 0; it < 2; ++it) {
            int id = tid + it * 256;
            int r = id >> 3, c8 = id & 7;
            int gr = row0 + r;
            uint4 pk = {0u, 0u, 0u, 0u};
            if (gr < N) {
                uint4 raw = *(const uint4*)(base + (size_t)gr * 64 + c8 * 8);
                unsigned int rw[4] = {raw.x, raw.y, raw.z, raw.w};
                unsigned int ow[4];
                #pragma unroll
                for (int q2 = 0; q2 < 4; ++q2) {
                    int col = c8 * 8 + q2 * 2;
                    float v0 = fmaxf(fmaf(sCoef[ci][col], bf2f(rw[q2] & 0xFFFFu),
                                          sCoef[ci + 1][col]), 0.f);
                    float v1 = fmaxf(fmaf(sCoef[ci][col + 1], bf2f(rw[q2] >> 16),
                                          sCoef[ci + 1][col + 1]), 0.f);
                    ow[q2] = (unsigned int)f2bf(v0) | ((unsigned int)f2bf(v1) << 16);
                }
                pk.x = ow[0]; pk.y = ow[1]; pk.z = ow[2]; pk.w = ow[3];
            }
            *(uint4*)&sIn[r][c8 * 8] = pk;
        }
        #pragma unroll
        for (int it = 0; it < 2; ++it) {
            int id = tid + it * 256;
            int nr = id >> 3, c8 = id & 7;
            uint4 w = *(const uint4*)(S.wT + (size_t)nr * K + ch * 64 + c8 * 8);
            *(uint4*)&sW[nr][c8 * 8] = w;
        }
        __syncthreads();
        bfrag a0 = *(const bfrag*)&sIn[16 * wv + l15][quad * 8];
        bfrag a1 = *(const bfrag*)&sIn[16 * wv + l15][32 + quad * 8];
        #pragma unroll
        for (int c = 0; c < 4; ++c) {
            bfrag b0 = *(const bfrag*)&sW[16 * c + l15][quad * 8];
            bfrag b1 = *(const bfrag*)&sW[16 * c + l15][32 + quad * 8];
            acc[c] = __builtin_amdgcn_mfma_f32_16x16x32_bf16(a0, b0, acc[c], 0, 0, 0);
            acc[c] = __builtin_amdgcn_mfma_f32_16x16x32_bf16(a1, b1, acc[c], 0, 0, 0);
        }
    }

    // epilogue (cached stores; outputs re-read by the next stage)
    float psv[4], pqv[4];
    #pragma unroll
    for (int c = 0; c < 4; ++c) {
        int col = 16 * c + l15;
        float b = sBias[col];
        float ps = 0.f, pq = 0.f;
        #pragma unroll
        for (int r = 0; r < 4; ++r) {
            int grow = row0 + 16 * wv + quad * 4 + r;
            if (grow < N) {
                float v = acc[c][r] + b;
                S.out[(size_t)grow * 64 + col] = f2bf(v);
                ps += v; pq += v * v;
            }
        }
        psv[c] = ps; pqv[c] = pq;
    }
    #pragma unroll
    for (int c = 0; c < 4; ++c) {
        float ps = psv[c], pq = pqv[c];
        ps += __shfl_xor(ps, 16, 64); pq += __shfl_xor(pq, 16, 64);
        ps += __shfl_xor(ps, 32, 64); pq += __shfl_xor(pq, 32, 64);
        if (l < 16) { sRedS[wv][16 * c + l] = ps; sRedQ[wv][16 * c + l] = pq; }
    }
    __syncthreads();
    if (tid < 64) {
        float s = sRedS[0][tid] + sRedS[1][tid] + sRedS[2][tid] + sRedS[3][tid];
        float q = sRedQ[0][tid] + sRedQ[1][tid] + sRedQ[2][tid] + sRedQ[3][tid];
        unsafeAtomicAdd(&S.ostats[tid], s);
        unsafeAtomicAdd(&S.ostats[64 + tid], q);
    }
}

// ---------------- merged final BN+ReLU apply (NT output) ----------------

struct SegA {
    const unsigned short* in; const float* st; const float* g; const float* be;
    float* out; int N; int blk0;
};
struct ApplyArgs { SegA s[2]; int nseg; };

__global__ __launch_bounds__(256) void bn_relu_apply_multi_k(ApplyArgs A)
{
    __shared__ float sa[64], sc[64];
    int si = 0;
    if (A.nseg > 1 && (int)blockIdx.x >= A.s[1].blk0) si = 1;
    const SegA S = A.s[si];
    int tid = threadIdx.x;
    if (tid < 64) {
        float s = S.st[tid], sq = S.st[64 + tid];
        float m = s / (float)S.N, v = sq / (float)S.N - m * m;
        float a = S.g[tid] * rsqrtf(v + 1e-5f);
        sa[tid] = a; sc[tid] = S.be[tid] - a * m;
    }
    __syncthreads();
    int idx = ((int)blockIdx.x - S.blk0) * 256 + tid;
    if (idx < S.N * 8) {
        int r = idx >> 3, c8 = idx & 7;
        uint4 raw = *(const uint4*)(S.in + (size_t)r * 64 + c8 * 8);
        unsigned int rw[4] = {raw.x, raw.y, raw.z, raw.w};
        float o[8];
        #pragma unroll
        for (int q = 0; q < 4; ++q) {
            int col = c8 * 8 + q * 2;
            o[q * 2 + 0] = fmaxf(fmaf(sa[col + 0], bf2f(rw[q] & 0xFFFFu), sc[col + 0]), 0.f);
            o[q * 2 + 1] = fmaxf(fmaf(sa[col + 1], bf2f(rw[q] >> 16), sc[col + 1]), 0.f);
        }
        f4v o0 = {o[0], o[1], o[2], o[3]}, o1 = {o[4], o[5], o[6], o[7]};
        __builtin_nontemporal_store(o0, (f4v*)(S.out + (size_t)r * 64 + c8 * 8));
        __builtin_nontemporal_store(o1, (f4v*)(S.out + (size_t)r * 64 + c8 * 8 + 4));
    }
}

extern "C" void kernel_launch(void* const* d_in, const int* in_sizes, int n_in,
                              void* d_out, int out_size, void* d_ws, size_t ws_size,
                              hipStream_t stream) {
    (void)n_in; (void)out_size; (void)ws_size;
    const float* x0 = (const float*)d_in[0];
    const float* x1 = (const float*)d_in[1];
    const float* x2 = (const float*)d_in[2];
    const int* up_index0 = (const int*)d_in[3];
    const int* up_index1 = (const int*)d_in[4];
    const int* bnd_src1  = (const int*)d_in[5];
    const int* bnd_dst1  = (const int*)d_in[6];
    const int* bnd_src2  = (const int*)d_in[7];
    const int* bnd_dst2  = (const int*)d_in[8];
    const float* up_W1 = (const float*)d_in[9];
    const float* up_b1 = (const float*)d_in[10];
    const float* up_g1 = (const float*)d_in[11];
    const float* up_be1= (const float*)d_in[12];
    const float* up_W2 = (const float*)d_in[13];
    const float* up_b2 = (const float*)d_in[14];
    const float* up_g2 = (const float*)d_in[15];
    const float* up_be2= (const float*)d_in[16];
    const float* bd_W1 = (const float*)d_in[17];
    const float* bd_b1 = (const float*)d_in[18];
    const float* bd_g1 = (const float*)d_in[19];
    const float* bd_be1= (const float*)d_in[20];
    const float* bd_W2 = (const float*)d_in[21];
    const float* bd_b2 = (const float*)d_in[22];
    const float* bd_g2 = (const float*)d_in[23];
    const float* bd_be2= (const float*)d_in[24];
    const float* cmb_W = (const float*)d_in[25];
    const float* cmb_b = (const float*)d_in[26];
    const float* cmb_g = (const float*)d_in[27];
    const float* cmb_be= (const float*)d_in[28];
    const float* epsP  = (const float*)d_in[29];

    const int EU0 = in_sizes[3] / 2, EU1 = in_sizes[4] / 2;
    const int EB1 = in_sizes[5],     EB2 = in_sizes[7];
    const int n0 = in_sizes[0] / 64, n1 = in_sizes[1] / 64, n2 = in_sizes[2] / 64;
    const int nMax02 = (n0 > n2) ? n0 : n2;

    float* outP = (float*)d_out;

    // ---- ws layout (all 16B-aligned) ----
    unsigned short* bufU = (unsigned short*)d_ws;              // n1*64 bf16  (hU1)
    unsigned short* bufB = bufU + (size_t)n1 * 64;             // nMax02*64 bf16 (hU0)
    float* stats = (float*)(bufB + (size_t)nMax02 * 64);       // 15*128 fp32
    int*   bsum  = (int*)(stats + 15 * 128);                   // 1024 ints
    unsigned short* wT = (unsigned short*)(bsum + 1024);       // 73728 bf16

    // Concatenated CSR storage in out2 region (dead until apply(L2))
    const int NT  = n0 + 2 * n1 + n2;
    const int oU0 = 0, oU1 = n0, oB1 = n0 + n1, oB2 = n0 + 2 * n1;
    const int eU0 = 0, eU1 = EU0, eB1 = EU0 + EU1, eB2 = EU0 + EU1 + EB1;
    int* curAll  = (int*)(outP + (size_t)(n0 + n1) * 64);
    int* esrcAll = curAll + NT;

    // intermediates (bf16, N*64 each):
    unsigned short* hU0 = bufB;                                            // ws
    unsigned short* hB0 = (unsigned short*)outP;                           // out0 lower half
    unsigned short* hU2 = (unsigned short*)outP + (size_t)n0 * 64;         // out0 upper half
    unsigned short* hU1 = bufU;                                            // ws
    unsigned short* hB1 = (unsigned short*)(outP + (size_t)n0 * 64);       // out1 lower half
    unsigned short* hB2 = (unsigned short*)(outP + (size_t)n0 * 64) + (size_t)n1 * 64; // out1 upper

    hipMemsetAsync(stats, 0, 15 * 128 * sizeof(float), stream);
    wprep_k<<<15, 256, 0, stream>>>(up_W1, up_W2, bd_W1, bd_W2, cmb_W, wT);

    // ---- XCD-ranged CSR build ----
    hipMemsetAsync(curAll, 0, (size_t)NT * sizeof(int), stream);
    hist_ranged_k<<<2048, 256, 0, stream>>>(
        up_index0 + EU0, up_index1 + EU1, bnd_dst1, bnd_dst2,
        EU0, EU1, EB1, EB2, oU0, oU1, oB1, oB2, curAll, NT);
    int nbScan = (NT + 2047) / 2048;
    scanA_k<<<nbScan, 256, 0, stream>>>(curAll, bsum, NT);
    scanB_k<<<1, 512, 0, stream>>>(bsum, nbScan);
    scanC_k<<<nbScan, 256, 0, stream>>>(curAll, bsum, NT);
    fill_ranged_k<<<2048, 256, 0, stream>>>(
        up_index0, up_index0 + EU0, up_index1, up_index1 + EU1,
        bnd_src1, bnd_dst1, bnd_src2, bnd_dst2,
        EU0, EU1, EB1, EB2, oU0, oU1, oB1, oB2, curAll, esrcAll, NT);

    auto S  = [&](int d, int i) { return stats + (size_t)(d * 5 + i) * 128; };
    auto WTf = [&](int d, int j) { return wT + (size_t)d * 24576 + (j < 4 ? j * 4096 : 16384); };

    const int nb0 = (n0 + 63) / 64, nb1 = (n1 + 63) / 64, nb2 = (n2 + 63) / 64;

    // ---- K1: fused up+bd stage-1 pairs, one segment per level ----
    {
        PairArgs A{}; A.esrc = esrcAll; A.epsP = epsP;
        A.s[0] = { curAll + oU0, nullptr, x0, nullptr, x0,
                   WTf(0,0), WTf(0,2), up_b1 + 0, bd_b1 + 0,
                   hU0, hB0, S(0,0), S(0,2), n0, 0, eU0, 0, 0 };
        A.s[1] = { curAll + oU1, curAll + oB1, x1, x0, x1,
                   WTf(1,0), WTf(1,2), up_b1 + 64, bd_b1 + 64,
                   hU1, hB1, S(1,0), S(1,2), n1, nb0, eU1, eB1, 1 };
        A.s[2] = { nullptr, curAll + oB2, nullptr, x1, x2,
                   WTf(2,0), WTf(2,2), up_b1 + 128, bd_b1 + 128,
                   hU2, hB2, S(2,0), S(2,2), n2, nb0 + nb1, 0, eB2, 2 };
        gemm_pair_k<<<nb0 + nb1 + nb2, 256, 0, stream>>>(A);
    }

    // ---- K2: all 6 stage-2 GEMMs (mode 1, in-place) ----
    {
        GemmArgs A{}; A.nseg = 6;
        auto& s = A.s;
        s[0] = { hU0, nullptr, S(0,0), up_g1 + 0, up_be1 + 0,
                 nullptr, nullptr, nullptr,
                 WTf(0,1), up_b2 + 0, hU0, S(0,1), n0, 0 };
        s[1] = { hB0, nullptr, S(0,2), bd_g1 + 0, bd_be1 + 0,
                 nullptr, nullptr, nullptr,
                 WTf(0,3), bd_b2 + 0, hB0, S(0,3), n0, nb0 };
        s[2] = { hU1, nullptr, S(1,0), up_g1 + 64, up_be1 + 64,
                 nullptr, nullptr, nullptr,
                 WTf(1,1), up_b2 + 64, hU1, S(1,1), n1, 2*nb0 };
        s[3] = { hB1, nullptr, S(1,2), bd_g1 + 64, bd_be1 + 64,
                 nullptr, nullptr, nullptr,
                 WTf(1,3), bd_b2 + 64, hB1, S(1,3), n1, 2*nb0 + nb1 };
        s[4] = { hU2, nullptr, S(2,0), up_g1 + 128, up_be1 + 128,
                 nullptr, nullptr, nullptr,
                 WTf(2,1), up_b2 + 128, hU2, S(2,1), n2, 2*nb0 + 2*nb1 };
        s[5] = { hB2, nullptr, S(2,2), bd_g1 + 128, bd_be1 + 128,
                 nullptr, nullptr, nullptr,
                 WTf(2,3), bd_b2 + 128, hB2, S(2,3), n2, 2*nb0 + 2*nb1 + nb2 };
        gemm_bn_multi_k<<<2*nb0 + 2*nb1 + 2*nb2, 256, 0, stream>>>(1, A);
    }

    // ---- K3: 3 cmb GEMMs (mode 2, out in-place over hU) ----
    {
        GemmArgs A{}; A.nseg = 3;
        auto& s = A.s;
        s[0] = { hU0, hB0, S(0,1), up_g2 + 0, up_be2 + 0,
                 S(0,3), bd_g2 + 0, bd_be2 + 0,
                 WTf(0,4), cmb_b + 0, hU0, S(0,4), n0, 0 };
        s[1] = { hU1, hB1, S(1,1), up_g2 + 64, up_be2 + 64,
                 S(1,3), bd_g2 + 64, bd_be2 + 64,
                 WTf(1,4), cmb_b + 64, hU1, S(1,4), n1, nb0 };
        s[2] = { hU2, hB2, S(2,1), up_g2 + 128, up_be2 + 128,
                 S(2,3), bd_g2 + 128, bd_be2 + 128,
                 WTf(2,4), cmb_b + 128, hU2, S(2,4), n2, nb0 + nb1 };
        gemm_bn_multi_k<<<nb0 + nb1 + nb2, 256, 0, stream>>>(2, A);
    }

    // ---- applies: L2 first (hU2 lives in out0 upper, which apply(L0) kills) ----
    {
        ApplyArgs A{}; A.nseg = 1;
        A.s[0] = { hU2, S(2,4), cmb_g + 128, cmb_be + 128,
                   outP + (size_t)(n0 + n1) * 64, n2, 0 };
        bn_relu_apply_multi_k<<<(n2 * 8 + 255) / 256, 256, 0, stream>>>(A);
    }
    {
        ApplyArgs A{}; A.nseg = 2;
        int ab0 = (n0 * 8 + 255) / 256;
        A.s[0] = { hU0, S(0,4), cmb_g + 0, cmb_be + 0, outP, n0, 0 };
        A.s[1] = { hU1, S(1,4), cmb_g + 64, cmb_be + 64,
                   outP + (size_t)n0 * 64, n1, ab0 };
        bn_relu_apply_multi_k<<<ab0 + (n1 * 8 + 255) / 256, 256, 0, stream>>>(A);
    }
}